// Round 9
// baseline (494.365 us; speedup 1.0000x reference)
//
#include <hip/hip_runtime.h>
#include <hip/hip_cooperative_groups.h>
#include <math.h>

namespace cg = cooperative_groups;

#define B 8
#define T 8192
#define D 512
#define M 512
#define POS 32
#define CHUNK 4
#define NCHUNK (T / CHUNK)     // 2048 fine chunks per batch
#define GRP 32                 // fine chunks per coarse group
#define NGRP (NCHUNK / GRP)    // 64 groups per batch
#define BM (B * M)             // 4096
#define KD 512                 // GEMM K (fourier part hoisted out)
#define BK 64

typedef __attribute__((ext_vector_type(8))) short short8;
typedef __attribute__((ext_vector_type(4))) short short4v;
typedef __attribute__((ext_vector_type(4))) float floatx4;

static __device__ inline unsigned short f2bf(float f) {
    unsigned int u = __float_as_uint(f);
    unsigned int r = (u + 0x7fffu + ((u >> 16) & 1u)) >> 16;   // RNE
    return (unsigned short)r;
}
static __device__ inline float bf2f(unsigned short h) {
    return __uint_as_float(((unsigned int)h) << 16);
}

// =========================================================================
// Cooperative mega-kernel: 256 blocks x 256 threads (1 block/CU guaranteed),
// 4 phases with grid.sync(). LDS: one 32 KB pool re-partitioned per phase.
// =========================================================================
__global__ __launch_bounds__(256, 1) void k_mega(
        const float* __restrict__ fe, const int* __restrict__ bounds,
        const float* __restrict__ W, const float* __restrict__ bias,
        float* __restrict__ cp, float* __restrict__ gsum,
        float* __restrict__ gx, float* __restrict__ ffout,
        short* __restrict__ Xh, short* __restrict__ Xl,
        short* __restrict__ WhT, short* __restrict__ WlT,
        float* __restrict__ out) {
    cg::grid_group grid = cg::this_grid();
    __shared__ short smem[16384];          // 32 KB
    int blk = blockIdx.x;
    int tid = threadIdx.x;

    // ================= Phase 1: chunk-scan | wsplit | ffout =================
#pragma unroll 1
    for (int job = blk; job < 896; job += 256) {
        if (job < 512) {
            // chunk-scan: b = job>>6, g = job&63; 256 threads, float2 lanes
            int b = job >> 6;
            int g = job & 63;
            int d2 = tid << 1;
            const float* src = fe + ((size_t)(b * T + g * (GRP * CHUNK)) * D + d2);
            float* cpb = cp + ((size_t)b * NCHUNK + (size_t)g * GRP) * D + d2;
            float2 acc = {0.f, 0.f};
#pragma unroll 4
            for (int c = 0; c < GRP; ++c) {
#pragma unroll
                for (int r = 0; r < CHUNK; ++r) {
                    float2 v = *(const float2*)(src + (size_t)(c * CHUNK + r) * D);
                    acc.x += v.x; acc.y += v.y;
                }
                *(float2*)(cpb + (size_t)c * D) = acc;
            }
            *(float2*)(gsum + ((size_t)b * NGRP + g) * D + d2) = acc;
        } else if (job < 640) {
            // wsplit: W[0:512][:] -> WhT/WlT bf16 [n][k]
            float* ws = (float*)smem;      // [32][65] = 8320 B
            int wb = job - 512;
            int k0 = (wb & 15) * 32;
            int n0 = (wb >> 4) * 64;
            __syncthreads();               // protect smem from previous use
            {
                int kk = tid >> 3;
                int nn = (tid & 7) << 3;
                const float* src = W + (size_t)(k0 + kk) * D + n0 + nn;
                float4 v0 = *(const float4*)src;
                float4 v1 = *(const float4*)(src + 4);
                float* wr = ws + kk * 65 + nn;
                wr[0] = v0.x; wr[1] = v0.y; wr[2] = v0.z; wr[3] = v0.w;
                wr[4] = v1.x; wr[5] = v1.y; wr[6] = v1.z; wr[7] = v1.w;
            }
            __syncthreads();
            int n = tid >> 2;
            int kq = (tid & 3) << 3;
            short8 hv, lv;
#pragma unroll
            for (int j = 0; j < 8; ++j) {
                float wv = ws[(kq + j) * 65 + n];
                unsigned short hb = f2bf(wv);
                hv[j] = (short)hb;
                lv[j] = (short)f2bf(wv - bf2f(hb));
            }
            size_t off = (size_t)(n0 + n) * KD + k0 + kq;
            *(short8*)(WhT + off) = hv;
            *(short8*)(WlT + off) = lv;
        } else {
            // ffout: 2 m per job
            int m = ((job - 640) << 1) + (tid >> 7);
            int n4 = (tid & 127) << 2;
            float pos = (float)m * (1.0f / 511.0f);
            float4 acc = *(const float4*)(bias + n4);
#pragma unroll
            for (int j = 0; j < 16; ++j) {
                float freq = expf(0.46051701859880914f * (float)j);  // 1000^(j/15)
                float ang = pos * freq;
                float s = sinf(ang), c = cosf(ang);
                float4 wsn = *(const float4*)(W + (size_t)(D + j) * D + n4);
                float4 wcn = *(const float4*)(W + (size_t)(D + 16 + j) * D + n4);
                acc.x += s * wsn.x + c * wcn.x;
                acc.y += s * wsn.y + c * wcn.y;
                acc.z += s * wsn.z + c * wcn.z;
                acc.w += s * wsn.w + c * wcn.w;
            }
            *(float4*)(ffout + (size_t)m * D + n4) = acc;
        }
    }
    __threadfence();
    grid.sync();

    // ================= Phase 2: exclusive scan of 64 coarse totals ==========
    {
        int gt = blk * 256 + tid;
        if (gt < B * D) {                  // 4096 columns on blocks 0..15
            int b = gt >> 9;
            int d = gt & 511;
            const float* gs = gsum + (size_t)b * NGRP * D + d;
            float* gxp = gx + (size_t)b * (NGRP + 1) * D + d;
            float acc = 0.f;
#pragma unroll
            for (int g = 0; g < NGRP; ++g) {
                gxp[(size_t)g * D] = acc;
                acc += gs[(size_t)g * D];
            }
            gxp[(size_t)NGRP * D] = acc;
        }
    }
    __threadfence();
    grid.sync();

    // ================= Phase 3: segment means -> Xh/Xl bf16 =================
    // chunk-prefix(c) = gx[b, c>>5] + (c&31 ? cp[b, c-1] : 0)
    {
        int sub = (blk << 1) + (tid >> 7);         // 512 subgroups/iteration
        int d4 = (tid & 127) << 2;
#pragma unroll 1
        for (int i = 0; i < 8; ++i) {
            int bm = sub + (i << 9);               // covers [0, 4096)
            int b = bm >> 9;
            int b0 = bounds[bm * 2 + 0];
            int b1 = bounds[bm * 2 + 1];
            int s = min(max(b0, 0), T - 1);
            int e = max(min(b1, T), s + 1);
            int cs_ = s >> 2, ce = e >> 2;

            const float* cpb = cp + (size_t)b * NCHUNK * D;
            const float* gxb = gx + (size_t)b * (NGRP + 1) * D;

            float4 acc = *(const float4*)(gxb + (size_t)(ce >> 5) * D + d4);
            if (ce & 31) {
                float4 v = *(const float4*)(cpb + (size_t)(ce - 1) * D + d4);
                acc.x += v.x; acc.y += v.y; acc.z += v.z; acc.w += v.w;
            }
            {
                float4 p = *(const float4*)(gxb + (size_t)(cs_ >> 5) * D + d4);
                acc.x -= p.x; acc.y -= p.y; acc.z -= p.z; acc.w -= p.w;
                if (cs_ & 31) {
                    float4 v = *(const float4*)(cpb + (size_t)(cs_ - 1) * D + d4);
                    acc.x -= v.x; acc.y -= v.y; acc.z -= v.z; acc.w -= v.w;
                }
            }

            const float* feb = fe + (size_t)b * T * D + d4;
            for (int t = ce * CHUNK; t < e; ++t) {      // <= 3 iters
                float4 v = *(const float4*)(feb + (size_t)t * D);
                acc.x += v.x; acc.y += v.y; acc.z += v.z; acc.w += v.w;
            }
            for (int t = cs_ * CHUNK; t < s; ++t) {     // <= 3 iters
                float4 v = *(const float4*)(feb + (size_t)t * D);
                acc.x -= v.x; acc.y -= v.y; acc.z -= v.z; acc.w -= v.w;
            }
            float inv = 1.0f / (float)(e - s);
            float x0 = acc.x * inv, x1 = acc.y * inv, x2 = acc.z * inv, x3 = acc.w * inv;

            unsigned short h0 = f2bf(x0), h1 = f2bf(x1), h2 = f2bf(x2), h3 = f2bf(x3);
            short4v hv, lv;
            hv[0] = (short)h0; hv[1] = (short)h1; hv[2] = (short)h2; hv[3] = (short)h3;
            lv[0] = (short)f2bf(x0 - bf2f(h0));
            lv[1] = (short)f2bf(x1 - bf2f(h1));
            lv[2] = (short)f2bf(x2 - bf2f(h2));
            lv[3] = (short)f2bf(x3 - bf2f(h3));
            size_t off = (size_t)bm * KD + d4;
            *(short4v*)(Xh + off) = hv;
            *(short4v*)(Xl + off) = lv;
        }
    }
    __threadfence();
    grid.sync();

    // ================= Phase 4: MFMA GEMM, 2 tiles per block ================
#define AH(h) (smem + (h) * 8192)
#define ALr(h) (smem + (h) * 8192 + 2048)
#define BH(h) (smem + (h) * 8192 + 4096)
#define BLr(h) (smem + (h) * 8192 + 6144)
    {
        int w = tid >> 6;
        int l = tid & 63;
        int lm = l & 15;
        int q = l >> 4;
        int wm = (w & 1) << 5;
        int wn = (w >> 1) << 5;
        int srow = tid >> 2;
        int skq = tid & 3;
        int sslot = skq ^ ((srow >> 1) & 3);
        int ldsoff = (srow << 5) + (sslot << 3);

        int aoff[2], boff[2];
#pragma unroll
        for (int mt = 0; mt < 2; ++mt) {
            int row = wm + (mt << 4) + lm;
            aoff[mt] = (row << 5) + ((q ^ ((row >> 1) & 3)) << 3);
        }
#pragma unroll
        for (int nt = 0; nt < 2; ++nt) {
            int row = wn + (nt << 4) + lm;
            boff[nt] = (row << 5) + ((q ^ ((row >> 1) & 3)) << 3);
        }

#pragma unroll 1
        for (int rep = 0; rep < 2; ++rep) {
            int tile = blk + (rep << 8);           // 512 tiles total
            int n0 = (tile & 7) << 6;
            int m0 = (tile >> 3) << 6;

            floatx4 acc[2][2];
#pragma unroll
            for (int i = 0; i < 2; ++i)
#pragma unroll
                for (int j = 0; j < 2; ++j)
                    acc[i][j] = (floatx4){0.f, 0.f, 0.f, 0.f};

            const short* gXh = Xh + (size_t)(m0 + srow) * KD + (skq << 3);
            const short* gXl = Xl + (size_t)(m0 + srow) * KD + (skq << 3);
            const short* gBh = WhT + (size_t)(n0 + srow) * KD + (skq << 3);
            const short* gBl = WlT + (size_t)(n0 + srow) * KD + (skq << 3);

            short8 pxh[2], pxl[2], pbh[2], pbl[2];
#pragma unroll
            for (int h = 0; h < 2; ++h) {
                pxh[h] = *(const short8*)(gXh + (h << 5));
                pxl[h] = *(const short8*)(gXl + (h << 5));
                pbh[h] = *(const short8*)(gBh + (h << 5));
                pbl[h] = *(const short8*)(gBl + (h << 5));
            }

            for (int k0 = 0; k0 < KD; k0 += BK) {   // 8 iterations
                __syncthreads();
#pragma unroll
                for (int h = 0; h < 2; ++h) {
                    *(short8*)(AH(h) + ldsoff) = pxh[h];
                    *(short8*)(ALr(h) + ldsoff) = pxl[h];
                    *(short8*)(BH(h) + ldsoff) = pbh[h];
                    *(short8*)(BLr(h) + ldsoff) = pbl[h];
                }
                __syncthreads();

                int kn = k0 + BK;
                if (kn < KD) {
#pragma unroll
                    for (int h = 0; h < 2; ++h) {
                        pxh[h] = *(const short8*)(gXh + kn + (h << 5));
                        pxl[h] = *(const short8*)(gXl + kn + (h << 5));
                        pbh[h] = *(const short8*)(gBh + kn + (h << 5));
                        pbl[h] = *(const short8*)(gBl + kn + (h << 5));
                    }
                }

#pragma unroll
                for (int h = 0; h < 2; ++h) {
                    short8 ah[2], al[2], bh[2], bl[2];
#pragma unroll
                    for (int mt = 0; mt < 2; ++mt) {
                        ah[mt] = *(const short8*)(AH(h) + aoff[mt]);
                        al[mt] = *(const short8*)(ALr(h) + aoff[mt]);
                    }
#pragma unroll
                    for (int nt = 0; nt < 2; ++nt) {
                        bh[nt] = *(const short8*)(BH(h) + boff[nt]);
                        bl[nt] = *(const short8*)(BLr(h) + boff[nt]);
                    }
#pragma unroll
                    for (int mt = 0; mt < 2; ++mt)
#pragma unroll
                        for (int nt = 0; nt < 2; ++nt) {
                            acc[mt][nt] = __builtin_amdgcn_mfma_f32_16x16x32_bf16(
                                ah[mt], bh[nt], acc[mt][nt], 0, 0, 0);
                            acc[mt][nt] = __builtin_amdgcn_mfma_f32_16x16x32_bf16(
                                ah[mt], bl[nt], acc[mt][nt], 0, 0, 0);
                            acc[mt][nt] = __builtin_amdgcn_mfma_f32_16x16x32_bf16(
                                al[mt], bh[nt], acc[mt][nt], 0, 0, 0);
                        }
                }
            }

#pragma unroll
            for (int mt = 0; mt < 2; ++mt) {
#pragma unroll
                for (int nt = 0; nt < 2; ++nt) {
                    int gcol = n0 + wn + (nt << 4) + lm;
#pragma unroll
                    for (int r = 0; r < 4; ++r) {
                        int grow = m0 + wm + (mt << 4) + (q << 2) + r;
                        float f = ffout[(size_t)(grow & (M - 1)) * D + gcol];
                        out[(size_t)grow * D + gcol] = acc[mt][nt][r] + f;
                    }
                }
            }
        }
    }
}

// =========================================================================
// Fallback: proven 4-kernel path (R6, 227.3 us) in case cooperative launch
// is rejected at runtime.
// =========================================================================
__global__ __launch_bounds__(256) void k_fusedA(const float* __restrict__ fe,
                                                const float* __restrict__ W,
                                                const float* __restrict__ bias,
                                                float* __restrict__ cp,
                                                float* __restrict__ gsum,
                                                short* __restrict__ WhT,
                                                short* __restrict__ WlT,
                                                float* __restrict__ ffout) {
    int blk = blockIdx.x;
    int tid = threadIdx.x;
    if (blk < 512) {
        int b = blk >> 6;
        int g = blk & 63;
        int d2 = tid << 1;
        const float* src = fe + ((size_t)(b * T + g * (GRP * CHUNK)) * D + d2);
        float* cpb = cp + ((size_t)b * NCHUNK + (size_t)g * GRP) * D + d2;
        float2 acc = {0.f, 0.f};
#pragma unroll 4
        for (int c = 0; c < GRP; ++c) {
#pragma unroll
            for (int r = 0; r < CHUNK; ++r) {
                float2 v = *(const float2*)(src + (size_t)(c * CHUNK + r) * D);
                acc.x += v.x; acc.y += v.y;
            }
            *(float2*)(cpb + (size_t)c * D) = acc;
        }
        *(float2*)(gsum + ((size_t)b * NGRP + g) * D + d2) = acc;
    } else if (blk < 640) {
        __shared__ float ws[32][65];
        int wb = blk - 512;
        int k0 = (wb & 15) * 32;
        int n0 = (wb >> 4) * 64;
        {
            int kk = tid >> 3;
            int nn = (tid & 7) << 3;
            const float* src = W + (size_t)(k0 + kk) * D + n0 + nn;
            float4 v0 = *(const float4*)src;
            float4 v1 = *(const float4*)(src + 4);
            ws[kk][nn + 0] = v0.x; ws[kk][nn + 1] = v0.y; ws[kk][nn + 2] = v0.z; ws[kk][nn + 3] = v0.w;
            ws[kk][nn + 4] = v1.x; ws[kk][nn + 5] = v1.y; ws[kk][nn + 6] = v1.z; ws[kk][nn + 7] = v1.w;
        }
        __syncthreads();
        int n = tid >> 2;
        int kq = (tid & 3) << 3;
        short8 hv, lv;
#pragma unroll
        for (int j = 0; j < 8; ++j) {
            float w = ws[kq + j][n];
            unsigned short hb = f2bf(w);
            hv[j] = (short)hb;
            lv[j] = (short)f2bf(w - bf2f(hb));
        }
        size_t off = (size_t)(n0 + n) * KD + k0 + kq;
        *(short8*)(WhT + off) = hv;
        *(short8*)(WlT + off) = lv;
    } else {
        int m = ((blk - 640) << 1) + (tid >> 7);
        int n4 = (tid & 127) << 2;
        float pos = (float)m * (1.0f / 511.0f);
        float4 acc = *(const float4*)(bias + n4);
#pragma unroll
        for (int j = 0; j < 16; ++j) {
            float freq = expf(0.46051701859880914f * (float)j);
            float ang = pos * freq;
            float s = sinf(ang), c = cosf(ang);
            float4 wsn = *(const float4*)(W + (size_t)(D + j) * D + n4);
            float4 wcn = *(const float4*)(W + (size_t)(D + 16 + j) * D + n4);
            acc.x += s * wsn.x + c * wcn.x;
            acc.y += s * wsn.y + c * wcn.y;
            acc.z += s * wsn.z + c * wcn.z;
            acc.w += s * wsn.w + c * wcn.w;
        }
        *(float4*)(ffout + (size_t)m * D + n4) = acc;
    }
}

__global__ __launch_bounds__(64) void k_scan_coarse(const float* __restrict__ gsum,
                                                    float* __restrict__ gx) {
    int b = blockIdx.x >> 3;
    int d = ((blockIdx.x & 7) << 6) + threadIdx.x;
    const float* gs = gsum + (size_t)b * NGRP * D + d;
    float* gxp = gx + (size_t)b * (NGRP + 1) * D + d;
    float acc = 0.f;
#pragma unroll
    for (int g = 0; g < NGRP; ++g) {
        gxp[(size_t)g * D] = acc;
        acc += gs[(size_t)g * D];
    }
    gxp[(size_t)NGRP * D] = acc;
}

__global__ __launch_bounds__(128) void k_buildx(const float* __restrict__ fe,
                                                const int* __restrict__ bounds,
                                                const float* __restrict__ cp,
                                                const float* __restrict__ gx,
                                                short* __restrict__ Xh,
                                                short* __restrict__ Xl) {
    int bm = blockIdx.x;
    int b = bm / M;
    int b0 = bounds[bm * 2 + 0];
    int b1 = bounds[bm * 2 + 1];
    int s = min(max(b0, 0), T - 1);
    int e = max(min(b1, T), s + 1);
    int cs_ = s >> 2, ce = e >> 2;
    int d4 = threadIdx.x << 2;

    const float* cpb = cp + (size_t)b * NCHUNK * D;
    const float* gxb = gx + (size_t)b * (NGRP + 1) * D;

    float4 acc = *(const float4*)(gxb + (size_t)(ce >> 5) * D + d4);
    if (ce & 31) {
        float4 v = *(const float4*)(cpb + (size_t)(ce - 1) * D + d4);
        acc.x += v.x; acc.y += v.y; acc.z += v.z; acc.w += v.w;
    }
    {
        float4 p = *(const float4*)(gxb + (size_t)(cs_ >> 5) * D + d4);
        acc.x -= p.x; acc.y -= p.y; acc.z -= p.z; acc.w -= p.w;
        if (cs_ & 31) {
            float4 v = *(const float4*)(cpb + (size_t)(cs_ - 1) * D + d4);
            acc.x -= v.x; acc.y -= v.y; acc.z -= v.z; acc.w -= v.w;
        }
    }

    const float* feb = fe + (size_t)b * T * D + d4;
    for (int t = ce * CHUNK; t < e; ++t) {
        float4 v = *(const float4*)(feb + (size_t)t * D);
        acc.x += v.x; acc.y += v.y; acc.z += v.z; acc.w += v.w;
    }
    for (int t = cs_ * CHUNK; t < s; ++t) {
        float4 v = *(const float4*)(feb + (size_t)t * D);
        acc.x -= v.x; acc.y -= v.y; acc.z -= v.z; acc.w -= v.w;
    }
    float inv = 1.0f / (float)(e - s);
    float x0 = acc.x * inv, x1 = acc.y * inv, x2 = acc.z * inv, x3 = acc.w * inv;

    unsigned short h0 = f2bf(x0), h1 = f2bf(x1), h2 = f2bf(x2), h3 = f2bf(x3);
    short4v hv, lv;
    hv[0] = (short)h0; hv[1] = (short)h1; hv[2] = (short)h2; hv[3] = (short)h3;
    lv[0] = (short)f2bf(x0 - bf2f(h0));
    lv[1] = (short)f2bf(x1 - bf2f(h1));
    lv[2] = (short)f2bf(x2 - bf2f(h2));
    lv[3] = (short)f2bf(x3 - bf2f(h3));
    size_t off = (size_t)bm * KD + d4;
    *(short4v*)(Xh + off) = hv;
    *(short4v*)(Xl + off) = lv;
}

__global__ __launch_bounds__(256) void k_gemm(const short* __restrict__ Xh,
                                              const short* __restrict__ Xl,
                                              const short* __restrict__ WhT,
                                              const short* __restrict__ WlT,
                                              const float* __restrict__ ffout,
                                              float* __restrict__ out) {
    __shared__ short Ah[2][64 * 32], Al[2][64 * 32];
    __shared__ short Bh[2][64 * 32], Bl[2][64 * 32];
    int n0 = (blockIdx.x & 7) << 6;
    int m0 = (blockIdx.x >> 3) << 6;
    int tid = threadIdx.x;
    int w = tid >> 6;
    int l = tid & 63;
    int lm = l & 15;
    int q = l >> 4;
    int wm = (w & 1) << 5;
    int wn = (w >> 1) << 5;

    floatx4 acc[2][2];
#pragma unroll
    for (int i = 0; i < 2; ++i)
#pragma unroll
        for (int j = 0; j < 2; ++j)
            acc[i][j] = (floatx4){0.f, 0.f, 0.f, 0.f};

    int srow = tid >> 2;
    int skq = tid & 3;
    int sslot = skq ^ ((srow >> 1) & 3);
    int ldsoff = (srow << 5) + (sslot << 3);
    const short* gXh = Xh + (size_t)(m0 + srow) * KD + (skq << 3);
    const short* gXl = Xl + (size_t)(m0 + srow) * KD + (skq << 3);
    const short* gBh = WhT + (size_t)(n0 + srow) * KD + (skq << 3);
    const short* gBl = WlT + (size_t)(n0 + srow) * KD + (skq << 3);

    int aoff[2], boff[2];
#pragma unroll
    for (int mt = 0; mt < 2; ++mt) {
        int row = wm + (mt << 4) + lm;
        aoff[mt] = (row << 5) + ((q ^ ((row >> 1) & 3)) << 3);
    }
#pragma unroll
    for (int nt = 0; nt < 2; ++nt) {
        int row = wn + (nt << 4) + lm;
        boff[nt] = (row << 5) + ((q ^ ((row >> 1) & 3)) << 3);
    }

    short8 pxh[2], pxl[2], pbh[2], pbl[2];
#pragma unroll
    for (int h = 0; h < 2; ++h) {
        pxh[h] = *(const short8*)(gXh + (h << 5));
        pxl[h] = *(const short8*)(gXl + (h << 5));
        pbh[h] = *(const short8*)(gBh + (h << 5));
        pbl[h] = *(const short8*)(gBl + (h << 5));
    }

    for (int k0 = 0; k0 < KD; k0 += BK) {
        __syncthreads();
#pragma unroll
        for (int h = 0; h < 2; ++h) {
            *(short8*)(&Ah[h][ldsoff]) = pxh[h];
            *(short8*)(&Al[h][ldsoff]) = pxl[h];
            *(short8*)(&Bh[h][ldsoff]) = pbh[h];
            *(short8*)(&Bl[h][ldsoff]) = pbl[h];
        }
        __syncthreads();

        int kn = k0 + BK;
        if (kn < KD) {
#pragma unroll
            for (int h = 0; h < 2; ++h) {
                pxh[h] = *(const short8*)(gXh + kn + (h << 5));
                pxl[h] = *(const short8*)(gXl + kn + (h << 5));
                pbh[h] = *(const short8*)(gBh + kn + (h << 5));
                pbl[h] = *(const short8*)(gBl + kn + (h << 5));
            }
        }

#pragma unroll
        for (int h = 0; h < 2; ++h) {
            short8 ah[2], al[2], bh[2], bl[2];
#pragma unroll
            for (int mt = 0; mt < 2; ++mt) {
                ah[mt] = *(const short8*)(&Ah[h][aoff[mt]]);
                al[mt] = *(const short8*)(&Al[h][aoff[mt]]);
            }
#pragma unroll
            for (int nt = 0; nt < 2; ++nt) {
                bh[nt] = *(const short8*)(&Bh[h][boff[nt]]);
                bl[nt] = *(const short8*)(&Bl[h][boff[nt]]);
            }
#pragma unroll
            for (int mt = 0; mt < 2; ++mt)
#pragma unroll
                for (int nt = 0; nt < 2; ++nt) {
                    acc[mt][nt] = __builtin_amdgcn_mfma_f32_16x16x32_bf16(
                        ah[mt], bh[nt], acc[mt][nt], 0, 0, 0);
                    acc[mt][nt] = __builtin_amdgcn_mfma_f32_16x16x32_bf16(
                        ah[mt], bl[nt], acc[mt][nt], 0, 0, 0);
                    acc[mt][nt] = __builtin_amdgcn_mfma_f32_16x16x32_bf16(
                        al[mt], bh[nt], acc[mt][nt], 0, 0, 0);
                }
        }
    }

#pragma unroll
    for (int mt = 0; mt < 2; ++mt) {
#pragma unroll
        for (int nt = 0; nt < 2; ++nt) {
            int gcol = n0 + wn + (nt << 4) + lm;
#pragma unroll
            for (int r = 0; r < 4; ++r) {
                int grow = m0 + wm + (mt << 4) + (q << 2) + r;
                float f = ffout[(size_t)(grow & (M - 1)) * D + gcol];
                out[(size_t)grow * D + gcol] = acc[mt][nt][r] + f;
            }
        }
    }
}

extern "C" void kernel_launch(void* const* d_in, const int* in_sizes, int n_in,
                              void* d_out, int out_size, void* d_ws, size_t ws_size,
                              hipStream_t stream) {
    const float* fe = (const float*)d_in[0];
    const int* bounds = (const int*)d_in[1];
    const float* W = (const float*)d_in[2];
    const float* bias = (const float*)d_in[3];
    float* out = (float*)d_out;

    float* cp = (float*)d_ws;                                  // 33.5 MB
    float* gsum = cp + (size_t)B * NCHUNK * D;                 // 1 MB
    float* gx = gsum + (size_t)B * NGRP * D;                   // 1.06 MB
    float* ffout = gx + (size_t)B * (NGRP + 1) * D;            // 1 MB
    short* Xh = (short*)(ffout + (size_t)M * D);               // 4 MB
    short* Xl = Xh + (size_t)BM * KD;                          // 4 MB
    short* WhT = Xl + (size_t)BM * KD;                         // 0.5 MB
    short* WlT = WhT + (size_t)KD * D;                         // 0.5 MB

    void* args[] = {(void*)&fe, (void*)&bounds, (void*)&W, (void*)&bias,
                    (void*)&cp, (void*)&gsum, (void*)&gx, (void*)&ffout,
                    (void*)&Xh, (void*)&Xl, (void*)&WhT, (void*)&WlT,
                    (void*)&out};
    hipError_t rc = hipLaunchCooperativeKernel((void*)k_mega, dim3(256),
                                               dim3(256), args, 0, stream);
    if (rc != hipSuccess) {
        (void)hipGetLastError();   // clear sticky error, use proven 4-kernel path
        k_fusedA<<<896, 256, 0, stream>>>(fe, W, bias, cp, gsum, WhT, WlT, ffout);
        k_scan_coarse<<<B * 8, 64, 0, stream>>>(gsum, gx);
        k_buildx<<<BM, 128, 0, stream>>>(fe, bounds, cp, gx, Xh, Xl);
        k_gemm<<<64 * 8, 256, 0, stream>>>(Xh, Xl, WhT, WlT, ffout, out);
    }
}

// Round 10
// 227.627 us; speedup vs baseline: 2.1718x; 2.1718x over previous
//
#include <hip/hip_runtime.h>
#include <math.h>

#define B 8
#define T 8192
#define D 512
#define M 512
#define POS 32
#define CHUNK 8
#define NCHUNK (T / CHUNK)     // 1024 fine chunks per batch
#define GRP 16                 // fine chunks per coarse group (128 rows/group)
#define NGRP (NCHUNK / GRP)    // 64 groups per batch
#define BM (B * M)             // 4096
#define KD 512                 // GEMM K (fourier part hoisted out)
#define BK 64

typedef __attribute__((ext_vector_type(8))) short short8;
typedef __attribute__((ext_vector_type(4))) short short4v;
typedef __attribute__((ext_vector_type(4))) float floatx4;

static __device__ inline unsigned short f2bf(float f) {
    unsigned int u = __float_as_uint(f);
    unsigned int r = (u + 0x7fffu + ((u >> 16) & 1u)) >> 16;   // RNE
    return (unsigned short)r;
}
static __device__ inline float bf2f(unsigned short h) {
    return __uint_as_float(((unsigned int)h) << 16);
}

// ================= KA: fused {chunk-scan | wsplit | ffout} ==================
// blocks [0,512): (b,g) 128-row group, 256 thr float2; cp[b, g*16+c, :] =
//                 intra-group inclusive prefix of 8-row chunk sums
// blocks [512,640): W[0:512][:] -> WhT/WlT bf16 [n][k]
// blocks [640,896): ffout[m][n] = FF(m) @ W[512:544] + b   (2 m per block)
__global__ __launch_bounds__(256) void k_fusedA(const float* __restrict__ fe,
                                                const float* __restrict__ W,
                                                const float* __restrict__ bias,
                                                float* __restrict__ cp,
                                                short* __restrict__ WhT,
                                                short* __restrict__ WlT,
                                                float* __restrict__ ffout) {
    int blk = blockIdx.x;
    int tid = threadIdx.x;
    if (blk < 512) {
        int b = blk >> 6;
        int g = blk & 63;
        int d2 = tid << 1;
        const float* src = fe + ((size_t)(b * T + g * (GRP * CHUNK)) * D + d2);
        float* cpb = cp + ((size_t)b * NCHUNK + (size_t)g * GRP) * D + d2;
        float2 acc = {0.f, 0.f};
#pragma unroll 4
        for (int c = 0; c < GRP; ++c) {
#pragma unroll
            for (int r = 0; r < CHUNK; ++r) {
                float2 v = *(const float2*)(src + (size_t)(c * CHUNK + r) * D);
                acc.x += v.x; acc.y += v.y;
            }
            *(float2*)(cpb + (size_t)c * D) = acc;
        }
        // group total == cp[b, g*16+15, :] (read directly by KB; no gsum)
    } else if (blk < 640) {
        // ---- wsplit
        __shared__ float ws[32][65];
        int wb = blk - 512;
        int k0 = (wb & 15) * 32;
        int n0 = (wb >> 4) * 64;
        {
            int kk = tid >> 3;
            int nn = (tid & 7) << 3;
            const float* src = W + (size_t)(k0 + kk) * D + n0 + nn;
            float4 v0 = *(const float4*)src;
            float4 v1 = *(const float4*)(src + 4);
            ws[kk][nn + 0] = v0.x; ws[kk][nn + 1] = v0.y; ws[kk][nn + 2] = v0.z; ws[kk][nn + 3] = v0.w;
            ws[kk][nn + 4] = v1.x; ws[kk][nn + 5] = v1.y; ws[kk][nn + 6] = v1.z; ws[kk][nn + 7] = v1.w;
        }
        __syncthreads();
        int n = tid >> 2;
        int kq = (tid & 3) << 3;
        short8 hv, lv;
#pragma unroll
        for (int j = 0; j < 8; ++j) {
            float w = ws[kq + j][n];
            unsigned short hb = f2bf(w);
            hv[j] = (short)hb;
            lv[j] = (short)f2bf(w - bf2f(hb));
        }
        size_t off = (size_t)(n0 + n) * KD + k0 + kq;
        *(short8*)(WhT + off) = hv;
        *(short8*)(WlT + off) = lv;
    } else {
        // ---- ffout: 2 m per block
        int m = ((blk - 640) << 1) + (tid >> 7);
        int n4 = (tid & 127) << 2;
        float pos = (float)m * (1.0f / 511.0f);
        float4 acc = *(const float4*)(bias + n4);
#pragma unroll
        for (int j = 0; j < 16; ++j) {
            float freq = expf(0.46051701859880914f * (float)j);  // 1000^(j/15)
            float ang = pos * freq;
            float s = sinf(ang), c = cosf(ang);
            float4 wsn = *(const float4*)(W + (size_t)(D + j) * D + n4);
            float4 wcn = *(const float4*)(W + (size_t)(D + 16 + j) * D + n4);
            acc.x += s * wsn.x + c * wcn.x;
            acc.y += s * wsn.y + c * wcn.y;
            acc.z += s * wsn.z + c * wcn.z;
            acc.w += s * wsn.w + c * wcn.w;
        }
        *(float4*)(ffout + (size_t)m * D + n4) = acc;
    }
}

// ================= KB: exclusive scan of 64 group totals per batch ==========
// grid = B*8 blocks (b x d-slice of 64), 64 threads; group total read from
// cp[b, g*GRP + GRP-1, :]
__global__ __launch_bounds__(64) void k_scan_coarse(const float* __restrict__ cp,
                                                    float* __restrict__ gx) {
    int b = blockIdx.x >> 3;
    int d = ((blockIdx.x & 7) << 6) + threadIdx.x;
    const float* cpb = cp + (size_t)b * NCHUNK * D + d;
    float* gxp = gx + (size_t)b * (NGRP + 1) * D + d;
    float acc = 0.f;
#pragma unroll
    for (int g = 0; g < NGRP; ++g) {
        gxp[(size_t)g * D] = acc;
        acc += cpb[(size_t)(g * GRP + GRP - 1) * D];
    }
    gxp[(size_t)NGRP * D] = acc;
}

// ================= KC: segment means -> Xh/Xl [4096][512] bf16 ==============
// chunk-prefix(c) = gx[b, c>>4] + (c&15 ? cp[b, c-1] : 0);  CHUNK=8 edges
__global__ __launch_bounds__(128) void k_buildx(const float* __restrict__ fe,
                                                const int* __restrict__ bounds,
                                                const float* __restrict__ cp,
                                                const float* __restrict__ gx,
                                                short* __restrict__ Xh,
                                                short* __restrict__ Xl) {
    int bm = blockIdx.x;
    int b = bm / M;
    int b0 = bounds[bm * 2 + 0];
    int b1 = bounds[bm * 2 + 1];
    int s = min(max(b0, 0), T - 1);
    int e = max(min(b1, T), s + 1);
    int cs_ = s >> 3, ce = e >> 3;
    int d4 = threadIdx.x << 2;

    const float* cpb = cp + (size_t)b * NCHUNK * D;
    const float* gxb = gx + (size_t)b * (NGRP + 1) * D;

    float4 acc = *(const float4*)(gxb + (size_t)(ce >> 4) * D + d4);
    if (ce & 15) {
        float4 v = *(const float4*)(cpb + (size_t)(ce - 1) * D + d4);
        acc.x += v.x; acc.y += v.y; acc.z += v.z; acc.w += v.w;
    }
    {
        float4 p = *(const float4*)(gxb + (size_t)(cs_ >> 4) * D + d4);
        acc.x -= p.x; acc.y -= p.y; acc.z -= p.z; acc.w -= p.w;
        if (cs_ & 15) {
            float4 v = *(const float4*)(cpb + (size_t)(cs_ - 1) * D + d4);
            acc.x -= v.x; acc.y -= v.y; acc.z -= v.z; acc.w -= v.w;
        }
    }

    const float* feb = fe + (size_t)b * T * D + d4;
    for (int t = ce * CHUNK; t < e; ++t) {           // <= 7 iters
        float4 v = *(const float4*)(feb + (size_t)t * D);
        acc.x += v.x; acc.y += v.y; acc.z += v.z; acc.w += v.w;
    }
    for (int t = cs_ * CHUNK; t < s; ++t) {          // <= 7 iters
        float4 v = *(const float4*)(feb + (size_t)t * D);
        acc.x -= v.x; acc.y -= v.y; acc.z -= v.z; acc.w -= v.w;
    }
    float inv = 1.0f / (float)(e - s);
    float x0 = acc.x * inv, x1 = acc.y * inv, x2 = acc.z * inv, x3 = acc.w * inv;

    unsigned short h0 = f2bf(x0), h1 = f2bf(x1), h2 = f2bf(x2), h3 = f2bf(x3);
    short4v hv, lv;
    hv[0] = (short)h0; hv[1] = (short)h1; hv[2] = (short)h2; hv[3] = (short)h3;
    lv[0] = (short)f2bf(x0 - bf2f(h0));
    lv[1] = (short)f2bf(x1 - bf2f(h1));
    lv[2] = (short)f2bf(x2 - bf2f(h2));
    lv[3] = (short)f2bf(x3 - bf2f(h3));
    size_t off = (size_t)bm * KD + d4;
    *(short4v*)(Xh + off) = hv;
    *(short4v*)(Xl + off) = lv;
}

// ================= KD: MFMA GEMM, Out = (Xh+Xl)@(Wh+Wl) + ffout =============
// 64x64 block tile, 256 threads (2x2 waves of 32x32), K=512, BK=64,
// register prefetch of next K-tile before compute.  (R6-verified, unchanged)
__global__ __launch_bounds__(256) void k_gemm(const short* __restrict__ Xh,
                                              const short* __restrict__ Xl,
                                              const short* __restrict__ WhT,
                                              const short* __restrict__ WlT,
                                              const float* __restrict__ ffout,
                                              float* __restrict__ out) {
    __shared__ short Ah[2][64 * 32], Al[2][64 * 32];
    __shared__ short Bh[2][64 * 32], Bl[2][64 * 32];     // 32 KB total
    int n0 = (blockIdx.x & 7) << 6;
    int m0 = (blockIdx.x >> 3) << 6;
    int tid = threadIdx.x;
    int w = tid >> 6;
    int l = tid & 63;
    int lm = l & 15;
    int q = l >> 4;
    int wm = (w & 1) << 5;
    int wn = (w >> 1) << 5;

    floatx4 acc[2][2];
#pragma unroll
    for (int i = 0; i < 2; ++i)
#pragma unroll
        for (int j = 0; j < 2; ++j)
            acc[i][j] = (floatx4){0.f, 0.f, 0.f, 0.f};

    int srow = tid >> 2;
    int skq = tid & 3;
    int sslot = skq ^ ((srow >> 1) & 3);
    int ldsoff = (srow << 5) + (sslot << 3);
    const short* gXh = Xh + (size_t)(m0 + srow) * KD + (skq << 3);
    const short* gXl = Xl + (size_t)(m0 + srow) * KD + (skq << 3);
    const short* gBh = WhT + (size_t)(n0 + srow) * KD + (skq << 3);
    const short* gBl = WlT + (size_t)(n0 + srow) * KD + (skq << 3);

    int aoff[2], boff[2];
#pragma unroll
    for (int mt = 0; mt < 2; ++mt) {
        int row = wm + (mt << 4) + lm;
        aoff[mt] = (row << 5) + ((q ^ ((row >> 1) & 3)) << 3);
    }
#pragma unroll
    for (int nt = 0; nt < 2; ++nt) {
        int row = wn + (nt << 4) + lm;
        boff[nt] = (row << 5) + ((q ^ ((row >> 1) & 3)) << 3);
    }

    short8 pxh[2], pxl[2], pbh[2], pbl[2];
#pragma unroll
    for (int h = 0; h < 2; ++h) {
        pxh[h] = *(const short8*)(gXh + (h << 5));
        pxl[h] = *(const short8*)(gXl + (h << 5));
        pbh[h] = *(const short8*)(gBh + (h << 5));
        pbl[h] = *(const short8*)(gBl + (h << 5));
    }

    for (int k0 = 0; k0 < KD; k0 += BK) {   // 8 iterations
        __syncthreads();
#pragma unroll
        for (int h = 0; h < 2; ++h) {
            *(short8*)(&Ah[h][ldsoff]) = pxh[h];
            *(short8*)(&Al[h][ldsoff]) = pxl[h];
            *(short8*)(&Bh[h][ldsoff]) = pbh[h];
            *(short8*)(&Bl[h][ldsoff]) = pbl[h];
        }
        __syncthreads();

        int kn = k0 + BK;
        if (kn < KD) {
#pragma unroll
            for (int h = 0; h < 2; ++h) {
                pxh[h] = *(const short8*)(gXh + kn + (h << 5));
                pxl[h] = *(const short8*)(gXl + kn + (h << 5));
                pbh[h] = *(const short8*)(gBh + kn + (h << 5));
                pbl[h] = *(const short8*)(gBl + kn + (h << 5));
            }
        }

#pragma unroll
        for (int h = 0; h < 2; ++h) {
            short8 ah[2], al[2], bh[2], bl[2];
#pragma unroll
            for (int mt = 0; mt < 2; ++mt) {
                ah[mt] = *(const short8*)(&Ah[h][aoff[mt]]);
                al[mt] = *(const short8*)(&Al[h][aoff[mt]]);
            }
#pragma unroll
            for (int nt = 0; nt < 2; ++nt) {
                bh[nt] = *(const short8*)(&Bh[h][boff[nt]]);
                bl[nt] = *(const short8*)(&Bl[h][boff[nt]]);
            }
#pragma unroll
            for (int mt = 0; mt < 2; ++mt)
#pragma unroll
                for (int nt = 0; nt < 2; ++nt) {
                    acc[mt][nt] = __builtin_amdgcn_mfma_f32_16x16x32_bf16(
                        ah[mt], bh[nt], acc[mt][nt], 0, 0, 0);
                    acc[mt][nt] = __builtin_amdgcn_mfma_f32_16x16x32_bf16(
                        ah[mt], bl[nt], acc[mt][nt], 0, 0, 0);
                    acc[mt][nt] = __builtin_amdgcn_mfma_f32_16x16x32_bf16(
                        al[mt], bh[nt], acc[mt][nt], 0, 0, 0);
                }
        }
    }

#pragma unroll
    for (int mt = 0; mt < 2; ++mt) {
#pragma unroll
        for (int nt = 0; nt < 2; ++nt) {
            int gcol = n0 + wn + (nt << 4) + lm;
#pragma unroll
            for (int r = 0; r < 4; ++r) {
                int grow = m0 + wm + (mt << 4) + (q << 2) + r;
                float f = ffout[(size_t)(grow & (M - 1)) * D + gcol];
                out[(size_t)grow * D + gcol] = acc[mt][nt][r] + f;
            }
        }
    }
}

extern "C" void kernel_launch(void* const* d_in, const int* in_sizes, int n_in,
                              void* d_out, int out_size, void* d_ws, size_t ws_size,
                              hipStream_t stream) {
    const float* fe = (const float*)d_in[0];
    const int* bounds = (const int*)d_in[1];
    const float* W = (const float*)d_in[2];
    const float* bias = (const float*)d_in[3];
    float* out = (float*)d_out;

    float* cp = (float*)d_ws;                                  // 8*1024*512 f32 = 16.8 MB
    float* gx = cp + (size_t)B * NCHUNK * D;                   // 8*65*512 = 1.06 MB
    float* ffout = gx + (size_t)B * (NGRP + 1) * D;            // 1 MB
    short* Xh = (short*)(ffout + (size_t)M * D);               // 4 MB
    short* Xl = Xh + (size_t)BM * KD;                          // 4 MB
    short* WhT = Xl + (size_t)BM * KD;                         // 0.5 MB
    short* WlT = WhT + (size_t)KD * D;                         // 0.5 MB

    k_fusedA<<<896, 256, 0, stream>>>(fe, W, bias, cp, WhT, WlT, ffout);
    k_scan_coarse<<<B * 8, 64, 0, stream>>>(cp, gx);
    k_buildx<<<BM, 128, 0, stream>>>(fe, bounds, cp, gx, Xh, Xl);
    k_gemm<<<64 * 8, 256, 0, stream>>>(Xh, Xl, WhT, WlT, ffout, out);
}